// Round 16
// baseline (363.767 us; speedup 1.0000x reference)
//
#include <hip/hip_runtime.h>
#include <math.h>

#define L_SEQ 1024
#define NB 4
#define NH 16
#define DH 64
#define BH_TOT (NB * NH)            // 64
#define GQ_TOT (BH_TOT * L_SEQ)     // 65536
#define NPOS 257                    // 2*128+1
#define QP_STRIDE 260               // padded Qp row stride (u16 elements)
#define LDK 72                      // LDS K-stride (bf16) for attn tiles
#define LDQP 72                     // stride for QpsP (u16)
#define LDPV 264                    // pvT row stride (u16)
#define LDK32 40                    // LDS stride for 128-tile gemms (BK=32 + pad)

typedef unsigned short ushort_t;
typedef __attribute__((ext_vector_type(8))) short bf16x8;
typedef __attribute__((ext_vector_type(4))) float f32x4;

__device__ inline ushort_t f2bf_rne(float x) {
    unsigned u = __float_as_uint(x);
    unsigned r = u + 0x7FFFu + ((u >> 16) & 1u);
    return (ushort_t)(r >> 16);
}
__device__ inline float bf2f(ushort_t h) {
    return __uint_as_float(((unsigned)h) << 16);
}
__device__ inline uint4 pack8hi(float4 a0, float4 a1) {
    float v[8] = {a0.x, a0.y, a0.z, a0.w, a1.x, a1.y, a1.z, a1.w};
    unsigned hh[4];
    #pragma unroll
    for (int j = 0; j < 4; j++)
        hh[j] = (unsigned)f2bf_rne(v[2*j]) | ((unsigned)f2bf_rne(v[2*j+1]) << 16);
    return (uint4){hh[0], hh[1], hh[2], hh[3]};
}

// ---------------------------------------------------------------------------
// split_f32_hi: A (fp32) -> hi bf16 only.
// ---------------------------------------------------------------------------
__global__ __launch_bounds__(256)
void split_f32_hi(const float* __restrict__ A, ushort_t* __restrict__ hi)
{
    const size_t base = ((size_t)blockIdx.x * 256 + threadIdx.x) * 8;
    *(uint4*)(hi + base) =
        pack8hi(*(const float4*)(A + base), *(const float4*)(A + base + 4));
}

// ---------------------------------------------------------------------------
// split_transpose3: Wq/Wk/Wv (z-indexed) -> contiguous wqkv hi/lo [3072][1024].
// ---------------------------------------------------------------------------
__global__ __launch_bounds__(256)
void split_transpose3(const float* __restrict__ Wq, const float* __restrict__ Wk,
                      const float* __restrict__ Wv, ushort_t* __restrict__ Thi,
                      ushort_t* __restrict__ Tlo)
{
    __shared__ float Ws[64][65];
    const int tid = threadIdx.x;
    const int k0 = blockIdx.x * 64;
    const int n0 = blockIdx.y * 64;
    const int z  = blockIdx.z;
    const float* W = (z == 0) ? Wq : (z == 1) ? Wk : Wv;
    ushort_t* Hh = Thi + (size_t)z * 1048576;
    ushort_t* Ll = Tlo + (size_t)z * 1048576;
    const int r  = tid >> 4;
    const int c4 = (tid & 15) * 4;
    #pragma unroll
    for (int i = 0; i < 4; i++) {
        float4 v = *(const float4*)(W + (size_t)(k0 + r + i*16) * 1024 + n0 + c4);
        Ws[r + i*16][c4+0] = v.x;
        Ws[r + i*16][c4+1] = v.y;
        Ws[r + i*16][c4+2] = v.z;
        Ws[r + i*16][c4+3] = v.w;
    }
    __syncthreads();
    #pragma unroll
    for (int i = 0; i < 4; i++) {
        const int nl = r + i*16;
        ushort_t h[4], l[4];
        #pragma unroll
        for (int j = 0; j < 4; j++) {
            float x = Ws[c4 + j][nl];
            h[j] = f2bf_rne(x);
            l[j] = f2bf_rne(x - bf2f(h[j]));
        }
        size_t off = (size_t)(n0 + nl) * 1024 + k0 + c4;
        uint2 H, L;
        H.x = (unsigned)h[0] | ((unsigned)h[1] << 16);
        H.y = (unsigned)h[2] | ((unsigned)h[3] << 16);
        L.x = (unsigned)l[0] | ((unsigned)l[1] << 16);
        L.y = (unsigned)l[2] | ((unsigned)l[3] << 16);
        *(uint2*)(Hh + off) = H;
        *(uint2*)(Ll + off) = L;
    }
}

// ---------------------------------------------------------------------------
// split_transpose: single-matrix variant (Wo).
// ---------------------------------------------------------------------------
__global__ __launch_bounds__(256)
void split_transpose(const float* __restrict__ W, ushort_t* __restrict__ Thi,
                     ushort_t* __restrict__ Tlo, int Kdim, int Ndim)
{
    __shared__ float Ws[64][65];
    const int tid = threadIdx.x;
    const int k0 = blockIdx.x * 64;
    const int n0 = blockIdx.y * 64;
    const int r  = tid >> 4;
    const int c4 = (tid & 15) * 4;
    #pragma unroll
    for (int i = 0; i < 4; i++) {
        float4 v = *(const float4*)(W + (size_t)(k0 + r + i*16) * Ndim + n0 + c4);
        Ws[r + i*16][c4+0] = v.x;
        Ws[r + i*16][c4+1] = v.y;
        Ws[r + i*16][c4+2] = v.z;
        Ws[r + i*16][c4+3] = v.w;
    }
    __syncthreads();
    #pragma unroll
    for (int i = 0; i < 4; i++) {
        const int nl = r + i*16;
        ushort_t h[4], l[4];
        #pragma unroll
        for (int j = 0; j < 4; j++) {
            float x = Ws[c4 + j][nl];
            h[j] = f2bf_rne(x);
            l[j] = f2bf_rne(x - bf2f(h[j]));
        }
        size_t off = (size_t)(n0 + nl) * Kdim + k0 + c4;
        uint2 H, L;
        H.x = (unsigned)h[0] | ((unsigned)h[1] << 16);
        H.y = (unsigned)h[2] | ((unsigned)h[3] << 16);
        L.x = (unsigned)l[0] | ((unsigned)l[1] << 16);
        L.y = (unsigned)l[2] | ((unsigned)l[3] << 16);
        *(uint2*)(Thi + off) = H;
        *(uint2*)(Tlo + off) = L;
    }
}

// ---------------------------------------------------------------------------
// prep_pvt: posV fp32 [257][64] -> global pvT bf16 [64 d][LDPV r].
// ---------------------------------------------------------------------------
__global__ __launch_bounds__(256)
void prep_pvt(const float* __restrict__ posV, ushort_t* __restrict__ pvTg)
{
    __shared__ float Ws[64][65];
    const int tid = threadIdx.x;
    const int c = blockIdx.x;
    {
        const int r  = tid >> 2;
        const int d0 = (tid & 3) * 16;
        const float* src = posV + (size_t)(c * 64 + r + 1) * 64 + d0;
        #pragma unroll
        for (int i = 0; i < 4; i++) {
            float4 v = *(const float4*)(src + i * 4);
            Ws[r][d0 + i*4 + 0] = v.x;
            Ws[r][d0 + i*4 + 1] = v.y;
            Ws[r][d0 + i*4 + 2] = v.z;
            Ws[r][d0 + i*4 + 3] = v.w;
        }
    }
    __syncthreads();
    {
        const int d  = tid >> 2;
        const int r0 = (tid & 3) * 16;
        #pragma unroll
        for (int k = 0; k < 16; k++)
            pvTg[(size_t)d * LDPV + c * 64 + r0 + k] = f2bf_rne(Ws[r0 + k][d]);
    }
}

// ---------------------------------------------------------------------------
// gemm_qkv128 (R14-proven): fused QKV, 128x128 tile, BK=32, reg prefetch,
// 2-term split MFMA. nb = n0>>10: 0 -> Q bf16; 1 -> K; 2 -> V^T.
// ---------------------------------------------------------------------------
__global__ __launch_bounds__(256)
void gemm_qkv128(const ushort_t* __restrict__ Ahi,
                 const ushort_t* __restrict__ Bhi, const ushort_t* __restrict__ Blo,
                 const float* __restrict__ bq, const float* __restrict__ bk,
                 const float* __restrict__ bv,
                 ushort_t* __restrict__ Qbu, ushort_t* __restrict__ Kbu,
                 ushort_t* __restrict__ Vtu)
{
    __shared__ ushort_t As[128 * LDK32];
    __shared__ ushort_t Bs[2][128 * LDK32];
    const int tid  = threadIdx.x;
    const int m0   = blockIdx.x * 128;
    const int n0   = blockIdx.y * 128;
    const int nb   = n0 >> 10;
    const int wave = tid >> 6, lane = tid & 63;
    const int wr = wave >> 1, wc = wave & 1;
    const int lr = lane & 15, lq = lane >> 4;
    const int K = 1024;

    const int sA0 = tid,       rA0 = sA0 >> 2, cA0 = (sA0 & 3) * 8;
    const int sA1 = 256 + tid, rA1 = sA1 >> 2, cA1 = (sA1 & 3) * 8;

    f32x4 acc[4][4];
    #pragma unroll
    for (int i = 0; i < 4; i++)
        #pragma unroll
        for (int j = 0; j < 4; j++)
            acc[i][j] = (f32x4){0.f, 0.f, 0.f, 0.f};

    uint4 pa0, pa1, pbh0, pbh1, pbl0, pbl1;
    {
        const size_t a0 = (size_t)(m0 + rA0) * K + cA0, a1 = (size_t)(m0 + rA1) * K + cA1;
        const size_t b0 = (size_t)(n0 + rA0) * K + cA0, b1 = (size_t)(n0 + rA1) * K + cA1;
        pa0  = *(const uint4*)(Ahi + a0); pa1  = *(const uint4*)(Ahi + a1);
        pbh0 = *(const uint4*)(Bhi + b0); pbh1 = *(const uint4*)(Bhi + b1);
        pbl0 = *(const uint4*)(Blo + b0); pbl1 = *(const uint4*)(Blo + b1);
    }

    for (int it = 0; it < 32; it++) {
        __syncthreads();
        *(uint4*)&As[rA0 * LDK32 + cA0]    = pa0;
        *(uint4*)&As[rA1 * LDK32 + cA1]    = pa1;
        *(uint4*)&Bs[0][rA0 * LDK32 + cA0] = pbh0;
        *(uint4*)&Bs[0][rA1 * LDK32 + cA1] = pbh1;
        *(uint4*)&Bs[1][rA0 * LDK32 + cA0] = pbl0;
        *(uint4*)&Bs[1][rA1 * LDK32 + cA1] = pbl1;
        __syncthreads();
        if (it < 31) {
            const int k0 = (it + 1) * 32;
            const size_t a0 = (size_t)(m0 + rA0) * K + k0 + cA0, a1 = (size_t)(m0 + rA1) * K + k0 + cA1;
            const size_t b0 = (size_t)(n0 + rA0) * K + k0 + cA0, b1 = (size_t)(n0 + rA1) * K + k0 + cA1;
            pa0  = *(const uint4*)(Ahi + a0); pa1  = *(const uint4*)(Ahi + a1);
            pbh0 = *(const uint4*)(Bhi + b0); pbh1 = *(const uint4*)(Bhi + b1);
            pbl0 = *(const uint4*)(Blo + b0); pbl1 = *(const uint4*)(Blo + b1);
        }

        bf16x8 ah[4], bh[4], bl[4];
        #pragma unroll
        for (int i = 0; i < 4; i++) {
            ah[i] = *(const bf16x8*)&As[(wr*64 + i*16 + lr) * LDK32 + lq*8];
            const int br = (wc*64 + i*16 + lr) * LDK32 + lq*8;
            bh[i] = *(const bf16x8*)&Bs[0][br];
            bl[i] = *(const bf16x8*)&Bs[1][br];
        }
        #pragma unroll
        for (int i = 0; i < 4; i++)
            #pragma unroll
            for (int j = 0; j < 4; j++) {
                acc[i][j] = __builtin_amdgcn_mfma_f32_16x16x32_bf16(ah[i], bh[j], acc[i][j], 0, 0, 0);
                acc[i][j] = __builtin_amdgcn_mfma_f32_16x16x32_bf16(ah[i], bl[j], acc[i][j], 0, 0, 0);
            }
    }

    const float* bp = (nb == 0) ? bq : (nb == 1) ? bk : bv;
    ushort_t* Cout = (nb == 0) ? Qbu : (nb == 1) ? Kbu : Vtu;
    #pragma unroll
    for (int j = 0; j < 4; j++) {
        const int colg = n0 + wc*64 + j*16 + lr;
        const int c1   = colg & 1023;
        const float bcol = bp[c1];
        const int h = c1 >> 6, dd = c1 & 63;
        #pragma unroll
        for (int i = 0; i < 4; i++) {
            #pragma unroll
            for (int r = 0; r < 4; r++) {
                const int m = m0 + wr*64 + i*16 + lq*4 + r;
                const float v = acc[i][j][r] + bcol;
                const int b = m >> 10, lp = m & 1023;
                const size_t off = (nb == 2)
                    ? ((size_t)(b * NH + h) * DH + dd) * L_SEQ + lp
                    : ((size_t)(b * NH + h) * L_SEQ + lp) * DH + dd;
                Cout[off] = f2bf_rne(v);
            }
        }
    }
}

// ---------------------------------------------------------------------------
// gemm_out128: final output GEMM, 128-tile, 3-term split, fp32 out.
// Same prefetch skeleton as gemm_qkv128; LDS 40 KB; grid (32, 8).
// ---------------------------------------------------------------------------
__global__ __launch_bounds__(256)
void gemm_out128(const ushort_t* __restrict__ Ahi, const ushort_t* __restrict__ Alo,
                 const ushort_t* __restrict__ Bhi, const ushort_t* __restrict__ Blo,
                 const float* __restrict__ bias, float* __restrict__ C)
{
    __shared__ ushort_t As[2][128 * LDK32];
    __shared__ ushort_t Bs[2][128 * LDK32];
    const int tid  = threadIdx.x;
    const int m0   = blockIdx.x * 128;
    const int n0   = blockIdx.y * 128;
    const int wave = tid >> 6, lane = tid & 63;
    const int wr = wave >> 1, wc = wave & 1;
    const int lr = lane & 15, lq = lane >> 4;
    const int K = 1024, N = 1024;

    const int sA0 = tid,       rA0 = sA0 >> 2, cA0 = (sA0 & 3) * 8;
    const int sA1 = 256 + tid, rA1 = sA1 >> 2, cA1 = (sA1 & 3) * 8;

    f32x4 acc[4][4];
    #pragma unroll
    for (int i = 0; i < 4; i++)
        #pragma unroll
        for (int j = 0; j < 4; j++)
            acc[i][j] = (f32x4){0.f, 0.f, 0.f, 0.f};

    uint4 pah0, pah1, pal0, pal1, pbh0, pbh1, pbl0, pbl1;
    {
        const size_t a0 = (size_t)(m0 + rA0) * K + cA0, a1 = (size_t)(m0 + rA1) * K + cA1;
        const size_t b0 = (size_t)(n0 + rA0) * K + cA0, b1 = (size_t)(n0 + rA1) * K + cA1;
        pah0 = *(const uint4*)(Ahi + a0); pah1 = *(const uint4*)(Ahi + a1);
        pal0 = *(const uint4*)(Alo + a0); pal1 = *(const uint4*)(Alo + a1);
        pbh0 = *(const uint4*)(Bhi + b0); pbh1 = *(const uint4*)(Bhi + b1);
        pbl0 = *(const uint4*)(Blo + b0); pbl1 = *(const uint4*)(Blo + b1);
    }

    for (int it = 0; it < 32; it++) {
        __syncthreads();
        *(uint4*)&As[0][rA0 * LDK32 + cA0] = pah0;
        *(uint4*)&As[0][rA1 * LDK32 + cA1] = pah1;
        *(uint4*)&As[1][rA0 * LDK32 + cA0] = pal0;
        *(uint4*)&As[1][rA1 * LDK32 + cA1] = pal1;
        *(uint4*)&Bs[0][rA0 * LDK32 + cA0] = pbh0;
        *(uint4*)&Bs[0][rA1 * LDK32 + cA1] = pbh1;
        *(uint4*)&Bs[1][rA0 * LDK32 + cA0] = pbl0;
        *(uint4*)&Bs[1][rA1 * LDK32 + cA1] = pbl1;
        __syncthreads();
        if (it < 31) {
            const int k0 = (it + 1) * 32;
            const size_t a0 = (size_t)(m0 + rA0) * K + k0 + cA0, a1 = (size_t)(m0 + rA1) * K + k0 + cA1;
            const size_t b0 = (size_t)(n0 + rA0) * K + k0 + cA0, b1 = (size_t)(n0 + rA1) * K + k0 + cA1;
            pah0 = *(const uint4*)(Ahi + a0); pah1 = *(const uint4*)(Ahi + a1);
            pal0 = *(const uint4*)(Alo + a0); pal1 = *(const uint4*)(Alo + a1);
            pbh0 = *(const uint4*)(Bhi + b0); pbh1 = *(const uint4*)(Bhi + b1);
            pbl0 = *(const uint4*)(Blo + b0); pbl1 = *(const uint4*)(Blo + b1);
        }

        bf16x8 ah[4], al[4], bh[4], bl[4];
        #pragma unroll
        for (int i = 0; i < 4; i++) {
            const int ar = (wr*64 + i*16 + lr) * LDK32 + lq*8;
            ah[i] = *(const bf16x8*)&As[0][ar];
            al[i] = *(const bf16x8*)&As[1][ar];
            const int br = (wc*64 + i*16 + lr) * LDK32 + lq*8;
            bh[i] = *(const bf16x8*)&Bs[0][br];
            bl[i] = *(const bf16x8*)&Bs[1][br];
        }
        #pragma unroll
        for (int i = 0; i < 4; i++)
            #pragma unroll
            for (int j = 0; j < 4; j++) {
                acc[i][j] = __builtin_amdgcn_mfma_f32_16x16x32_bf16(ah[i], bh[j], acc[i][j], 0, 0, 0);
                acc[i][j] = __builtin_amdgcn_mfma_f32_16x16x32_bf16(ah[i], bl[j], acc[i][j], 0, 0, 0);
                acc[i][j] = __builtin_amdgcn_mfma_f32_16x16x32_bf16(al[i], bh[j], acc[i][j], 0, 0, 0);
            }
    }

    #pragma unroll
    for (int j = 0; j < 4; j++) {
        const int colg = n0 + wc*64 + j*16 + lr;
        const float bcol = bias[colg];
        #pragma unroll
        for (int i = 0; i < 4; i++) {
            #pragma unroll
            for (int r = 0; r < 4; r++) {
                const int m = m0 + wr*64 + i*16 + lq*4 + r;
                C[(size_t)m * N + colg] = acc[i][j][r] + bcol;
            }
        }
    }
}

// ---------------------------------------------------------------------------
// qp_mfma: Qp[65536 x 257] = Q @ posK^T via MFMA, no LDS.
// ---------------------------------------------------------------------------
__global__ __launch_bounds__(256)
void qp_mfma(const ushort_t* __restrict__ Qu, const float* __restrict__ posK,
             ushort_t* __restrict__ Qpu)
{
    const int tid = threadIdx.x;
    const size_t m0 = (size_t)blockIdx.x * 64;
    const int n0 = blockIdx.y * 64;
    const int wave = tid >> 6, lane = tid & 63;
    const int wm = (wave >> 1) * 32, wn = (wave & 1) * 32;
    const int lr = lane & 15, lq = lane >> 4;

    bf16x8 af[2][2];
    #pragma unroll
    for (int i = 0; i < 2; i++) {
        const ushort_t* qrow = Qu + (m0 + wm + i*16 + lr) * DH;
        #pragma unroll
        for (int kc = 0; kc < 2; kc++)
            af[i][kc] = *(const bf16x8*)(qrow + kc*32 + lq*8);
    }
    bf16x8 bf[2][2];
    #pragma unroll
    for (int j = 0; j < 2; j++) {
        int n = n0 + wn + j*16 + lr;
        const float* krow = posK + (size_t)(n < 256 ? n : 256) * DH;
        #pragma unroll
        for (int kc = 0; kc < 2; kc++) {
            const float* s = krow + kc*32 + lq*8;
            uint4 u = pack8hi(*(const float4*)s, *(const float4*)(s + 4));
            bf[j][kc] = *(bf16x8*)&u;
        }
    }

    f32x4 acc[2][2];
    #pragma unroll
    for (int i = 0; i < 2; i++)
        #pragma unroll
        for (int j = 0; j < 2; j++)
            acc[i][j] = (f32x4){0.f, 0.f, 0.f, 0.f};
    #pragma unroll
    for (int kc = 0; kc < 2; kc++)
        #pragma unroll
        for (int i = 0; i < 2; i++)
            #pragma unroll
            for (int j = 0; j < 2; j++)
                acc[i][j] = __builtin_amdgcn_mfma_f32_16x16x32_bf16(af[i][kc], bf[j][kc], acc[i][j], 0, 0, 0);

    #pragma unroll
    for (int i = 0; i < 2; i++)
        #pragma unroll
        for (int j = 0; j < 2; j++) {
            const int n = n0 + wn + j*16 + lr;
            if (n < NPOS) {
                #pragma unroll
                for (int r = 0; r < 4; r++) {
                    const size_t m = m0 + wm + i*16 + lq*4 + r;
                    Qpu[m * QP_STRIDE + n] = f2bf_rne(acc[i][j][r]);
                }
            }
        }
}

// ---------------------------------------------------------------------------
// attn v13 = v12 with COALESCED Qps prefetch. v9-v12 prefetched via
// (row = qw + lane>>2, colphase = (lane&3)*16): each load inst touched
// 16 rows x 4 phases = 16-32 cache lines. Now element c = (row 4c+wave,
// col lane): one row per inst, lanes contiguous -> 1-2 lines. Same values,
// same timing (register prefetch a full ktile ahead); LDS write is
// stride-1 u16 (2-way, free).
// ---------------------------------------------------------------------------
__global__ __launch_bounds__(256)
void attn_kernel(const ushort_t* __restrict__ Qu, const ushort_t* __restrict__ Ku,
                 const ushort_t* __restrict__ Vtu, const ushort_t* __restrict__ Qpu,
                 const float* __restrict__ pm,
                 ushort_t* __restrict__ SbandU,
                 ushort_t* __restrict__ O1a, ushort_t* __restrict__ O1b,
                 float* __restrict__ lsum2, float* __restrict__ clo2,
                 float* __restrict__ chi2)
{
    __shared__ ushort_t Ks[64 * LDK];
    __shared__ ushort_t Vs[64 * LDK];
    __shared__ ushort_t QpsP[64 * LDQP];
    __shared__ float mk[64];

    const int tid = threadIdx.x;
    const int blk = blockIdx.x;
    const int bh  = blk >> 5;
    const int qb  = (blk >> 1) & 15;
    const int ks  = blk & 1;
    const int b   = bh >> 4;
    const int q0  = qb * 64;
    const size_t gq0 = (size_t)bh * L_SEQ + q0;
    const int wave = tid >> 6, lane = tid & 63;
    const int lr = lane & 15, lq = lane >> 4;
    const int qw = wave * 16;

    const int sr0 = tid >> 3,          sc0 = (tid & 7) * 8;
    const int sr1 = (256 + tid) >> 3,  sc1 = ((256 + tid) & 7) * 8;

    const ushort_t* Kg  = Ku  + (size_t)bh * (L_SEQ * DH);
    const ushort_t* Vtg = Vtu + (size_t)bh * (DH * L_SEQ);

    bf16x8 qa[2];
    {
        const ushort_t* qrow = Qu + (gq0 + qw + lr) * DH;
        #pragma unroll
        for (int kc = 0; kc < 2; kc++)
            qa[kc] = *(const bf16x8*)(qrow + kc * 32 + lq * 8);
    }

    if (ks == 0 && tid < 64) {
        const int q = q0 + tid;
        ushort_t* bandRow = SbandU + (gq0 + tid) * 256;
        for (int j = 0; j < 127 - q; j++)    bandRow[j] = 0;
        for (int j = 254; j > 1150 - q; j--) bandRow[j] = 0;
        bandRow[255] = 0;
    }

    f32x4 Oacc[4];
    #pragma unroll
    for (int j = 0; j < 4; j++) Oacc[j] = (f32x4){0.f, 0.f, 0.f, 0.f};
    float lpart[4] = {}, clpart[4] = {}, chpart[4] = {};

    uint4 kva0, kva1, kvb0, kvb1;
    ushort_t qpr[16];
    float mkr = 0.f;
    {
        const int k0 = ks * 512;
        kva0 = *(const uint4*)(Kg + (size_t)(k0 + sr0) * DH + sc0);
        kva1 = *(const uint4*)(Kg + (size_t)(k0 + sr1) * DH + sc1);
        kvb0 = *(const uint4*)(Vtg + (size_t)sr0 * L_SEQ + k0 + sc0);
        kvb1 = *(const uint4*)(Vtg + (size_t)sr1 * L_SEQ + k0 + sc1);
        #pragma unroll
        for (int c = 0; c < 16; c++) {
            const int ql = 4*c + wave;
            int rel = k0 + lane - q0 - ql;
            rel = rel < -128 ? -128 : (rel > 128 ? 128 : rel);
            qpr[c] = Qpu[(gq0 + ql) * QP_STRIDE + rel + 128];
        }
        if (tid < 64) mkr = pm[b * L_SEQ + k0 + tid];
    }

    for (int t = 0; t < 8; t++) {
        const int k0 = (ks * 8 + t) * 64;
        __syncthreads();   // (a)

        *(uint4*)&Ks[sr0 * LDK + sc0] = kva0;
        *(uint4*)&Ks[sr1 * LDK + sc1] = kva1;
        *(uint4*)&Vs[sr0 * LDK + sc0] = kvb0;
        *(uint4*)&Vs[sr1 * LDK + sc1] = kvb1;
        #pragma unroll
        for (int c = 0; c < 16; c++)
            QpsP[(4*c + wave) * LDQP + lane] = qpr[c];
        if (tid < 64) mk[tid] = mkr;
        __syncthreads();   // (b)

        if (t < 7) {
            const int k0n = k0 + 64;
            kva0 = *(const uint4*)(Kg + (size_t)(k0n + sr0) * DH + sc0);
            kva1 = *(const uint4*)(Kg + (size_t)(k0n + sr1) * DH + sc1);
            kvb0 = *(const uint4*)(Vtg + (size_t)sr0 * L_SEQ + k0n + sc0);
            kvb1 = *(const uint4*)(Vtg + (size_t)sr1 * L_SEQ + k0n + sc1);
            #pragma unroll
            for (int c = 0; c < 16; c++) {
                const int ql = 4*c + wave;
                int rel = k0n + lane - q0 - ql;
                rel = rel < -128 ? -128 : (rel > 128 ? 128 : rel);
                qpr[c] = Qpu[(gq0 + ql) * QP_STRIDE + rel + 128];
            }
            if (tid < 64) mkr = pm[b * L_SEQ + k0n + tid];
        }

        f32x4 Sacc[4];
        #pragma unroll
        for (int j = 0; j < 4; j++) Sacc[j] = (f32x4){0.f, 0.f, 0.f, 0.f};
        #pragma unroll
        for (int kc = 0; kc < 2; kc++) {
            #pragma unroll
            for (int j = 0; j < 4; j++) {
                bf16x8 kb = *(const bf16x8*)&Ks[(j*16 + lr) * LDK + kc*32 + lq*8];
                Sacc[j] = __builtin_amdgcn_mfma_f32_16x16x32_bf16(qa[kc], kb, Sacc[j], 0, 0, 0);
            }
        }

        ushort_t pb[4][4];
        #pragma unroll
        for (int r = 0; r < 4; r++) {
            const int ql = qw + lq*4 + r;
            const int q  = q0 + ql;
            const size_t gq = gq0 + ql;
            ushort_t* bandRow = SbandU + gq * 256 + 127;
            #pragma unroll
            for (int j = 0; j < 4; j++) {
                const int kl = j*16 + lr;
                const int k  = k0 + kl;
                const int rel = k - q;
                float s = (Sacc[j][r] + bf2f(QpsP[ql * LDQP + kl])) * 0.125f;
                s *= mk[kl];
                const float p = __expf(s);
                lpart[r] += p;
                const ushort_t ph = f2bf_rne(p);
                if (rel <= -128)      clpart[r] += p;
                else if (rel >= 128)  chpart[r] += p;
                else                  bandRow[rel] = ph;
                pb[j][r] = ph;
            }
        }

        #pragma unroll
        for (int r = 0; r < 4; r++)
            #pragma unroll
            for (int j = 0; j < 4; j++)
                QpsP[(qw + lq*4 + r) * LDQP + j*16 + lr] = pb[j][r];

        #pragma unroll
        for (int kc = 0; kc < 2; kc++) {
            bf16x8 pa = *(const bf16x8*)&QpsP[(qw + lr) * LDQP + kc*32 + lq*8];
            #pragma unroll
            for (int j = 0; j < 4; j++) {
                bf16x8 vb = *(const bf16x8*)&Vs[(j*16 + lr) * LDK + kc*32 + lq*8];
                Oacc[j] = __builtin_amdgcn_mfma_f32_16x16x32_bf16(pa, vb, Oacc[j], 0, 0, 0);
            }
        }
    }

    #pragma unroll
    for (int off = 1; off < 16; off <<= 1) {
        #pragma unroll
        for (int r = 0; r < 4; r++) {
            lpart[r]  += __shfl_xor(lpart[r],  off, 64);
            clpart[r] += __shfl_xor(clpart[r], off, 64);
            chpart[r] += __shfl_xor(chpart[r], off, 64);
        }
    }
    if (lr == 0) {
        #pragma unroll
        for (int r = 0; r < 4; r++) {
            const size_t o = (size_t)ks * GQ_TOT + gq0 + qw + lq*4 + r;
            lsum2[o] = lpart[r];
            clo2[o]  = clpart[r];
            chi2[o]  = chpart[r];
        }
    }

    ushort_t* O1o = ks ? O1b : O1a;
    #pragma unroll
    for (int j = 0; j < 4; j++)
        #pragma unroll
        for (int r = 0; r < 4; r++)
            O1o[(gq0 + qw + lq*4 + r) * DH + j*16 + lr] = f2bf_rne(Oacc[j][r]);
}

// ---------------------------------------------------------------------------
// post_mfma: O2 = band @ posV^T via MFMA; O1 partials bf16.
// ---------------------------------------------------------------------------
__global__ __launch_bounds__(256)
void post_mfma(const ushort_t* __restrict__ SbandU, const ushort_t* __restrict__ pvTg,
               const ushort_t* __restrict__ O1a, const ushort_t* __restrict__ O1b,
               const float* __restrict__ lsum2, const float* __restrict__ clo2,
               const float* __restrict__ chi2, const float* __restrict__ posV,
               ushort_t* __restrict__ athi, ushort_t* __restrict__ atlo)
{
    __shared__ ushort_t pvT[64 * LDPV];
    const int tid = threadIdx.x;
    const size_t q0 = (size_t)blockIdx.x * 64;
    const int wave = tid >> 6, lane = tid & 63;
    const int w0 = wave >> 1, w1 = wave & 1;
    const int lr = lane & 15, lq = lane >> 4;

    {
        const unsigned* src = (const unsigned*)pvTg;
        unsigned* dst = (unsigned*)pvT;
        for (int i = tid; i < 64 * LDPV / 2; i += 256) dst[i] = src[i];
    }
    __syncthreads();

    f32x4 acc[2][2];
    #pragma unroll
    for (int i = 0; i < 2; i++)
        #pragma unroll
        for (int j = 0; j < 2; j++)
            acc[i][j] = (f32x4){0.f, 0.f, 0.f, 0.f};

    const ushort_t* bandB = SbandU + q0 * 256;
    #pragma unroll
    for (int kc = 0; kc < 8; kc++) {
        bf16x8 a[2], bv[2];
        #pragma unroll
        for (int i = 0; i < 2; i++) {
            a[i]  = *(const bf16x8*)&bandB[(size_t)(w0*32 + i*16 + lr) * 256 + kc*32 + lq*8];
            bv[i] = *(const bf16x8*)&pvT[(w1*32 + i*16 + lr) * LDPV + kc*32 + lq*8];
        }
        #pragma unroll
        for (int i = 0; i < 2; i++)
            #pragma unroll
            for (int j = 0; j < 2; j++)
                acc[i][j] = __builtin_amdgcn_mfma_f32_16x16x32_bf16(a[i], bv[j], acc[i][j], 0, 0, 0);
    }

    #pragma unroll
    for (int i = 0; i < 2; i++) {
        #pragma unroll
        for (int r = 0; r < 4; r++) {
            const int ql = w0*32 + i*16 + lq*4 + r;
            const size_t gq = q0 + ql;
            const float li = lsum2[gq] + lsum2[GQ_TOT + gq];
            const float cl = clo2[gq]  + clo2[GQ_TOT + gq];
            const float ch = chi2[gq]  + chi2[GQ_TOT + gq];
            const float inv = 1.0f / li;
            const int b  = (int)(gq >> 14);
            const int h  = (int)((gq >> 10) & 15);
            const int lp = (int)(gq & 1023);
            const size_t obase = ((size_t)(b * L_SEQ + lp) * 1024) + h * 64;
            #pragma unroll
            for (int j = 0; j < 2; j++) {
                const int dd = w1*32 + j*16 + lr;
                float o = bf2f(O1a[gq * DH + dd]) + bf2f(O1b[gq * DH + dd])
                        + acc[i][j][r]
                        + cl * posV[dd] + ch * posV[256 * 64 + dd];
                o *= inv;
                const ushort_t hh = f2bf_rne(o);
                const ushort_t ll = f2bf_rne(o - bf2f(hh));
                athi[obase + dd] = hh;
                atlo[obase + dd] = ll;
            }
        }
    }
}

// ---------------------------------------------------------------------------
extern "C" void kernel_launch(void* const* d_in, const int* in_sizes, int n_in,
                              void* d_out, int out_size, void* d_ws, size_t ws_size,
                              hipStream_t stream)
{
    const float* x    = (const float*)d_in[0];
    const float* pmk  = (const float*)d_in[1];
    const float* Wq   = (const float*)d_in[2];
    const float* bq   = (const float*)d_in[3];
    const float* Wk   = (const float*)d_in[4];
    const float* bk   = (const float*)d_in[5];
    const float* Wv   = (const float*)d_in[6];
    const float* bv   = (const float*)d_in[7];
    const float* Wo   = (const float*)d_in[8];
    const float* bo   = (const float*)d_in[9];
    const float* posK = (const float*)d_in[10];
    const float* posV = (const float*)d_in[11];
    float* out = (float*)d_out;

    // workspace carve-up (u16 first, then f32)
    ushort_t* u = (ushort_t*)d_ws;
    ushort_t* Qbu    = u;                                 // GQ*64 u16
    ushort_t* Kbu    = Qbu + (size_t)GQ_TOT * DH;
    ushort_t* Vtu    = Kbu + (size_t)GQ_TOT * DH;         // V^T
    ushort_t* Qpu    = Vtu + (size_t)GQ_TOT * DH;         // GQ*260
    ushort_t* SbandU = Qpu + (size_t)GQ_TOT * QP_STRIDE;  // GQ*256
    ushort_t* athi   = SbandU + (size_t)GQ_TOT * 256;
    ushort_t* atlo   = athi + (size_t)GQ_TOT * DH;
    ushort_t* O1a    = atlo + (size_t)GQ_TOT * DH;        // bf16 partials
    ushort_t* O1b    = O1a  + (size_t)GQ_TOT * DH;
    ushort_t* pvTg   = O1b  + (size_t)GQ_TOT * DH;
    float* lsum2 = (float*)(pvTg + 64 * LDPV + 64);       // 4B-aligned
    float* clo2  = lsum2 + 2 * (size_t)GQ_TOT;
    float* chi2  = clo2  + 2 * (size_t)GQ_TOT;

    // bf16 scratch aliased into the Sband region (disjoint lifetimes)
    ushort_t* bb    = SbandU;
    ushort_t* xhi   = bb;
    ushort_t* wqkvh = xhi + 4194304;       // [3072][1024]
    ushort_t* wqkvl = wqkvh + 3145728;
    ushort_t* woh   = bb;
    ushort_t* wol   = woh + 1048576;

    dim3 gb(256);

    split_f32_hi<<<dim3(2048), gb, 0, stream>>>(x, xhi);
    split_transpose3<<<dim3(16, 16, 3), gb, 0, stream>>>(Wq, Wk, Wv, wqkvh, wqkvl);
    prep_pvt<<<dim3(4), gb, 0, stream>>>(posV, pvTg);
    gemm_qkv128<<<dim3(32, 24), gb, 0, stream>>>(xhi, wqkvh, wqkvl, bq, bk, bv,
                                                 Qbu, Kbu, Vtu);
    qp_mfma<<<dim3(1024, 5), gb, 0, stream>>>(Qbu, posK, Qpu);
    attn_kernel<<<dim3(2048), gb, 0, stream>>>(Qbu, Kbu, Vtu, Qpu, pmk,
                                               SbandU, O1a, O1b, lsum2, clo2, chi2);
    post_mfma<<<dim3(GQ_TOT / 64), gb, 0, stream>>>(SbandU, pvTg, O1a, O1b, lsum2,
                                                    clo2, chi2, posV, athi, atlo);
    split_transpose<<<dim3(16, 16), gb, 0, stream>>>(Wo, woh, wol, 1024, 1024);
    gemm_out128<<<dim3(32, 8), gb, 0, stream>>>(athi, atlo, woh, wol, bo, out);
}